// Round 10
// baseline (147.182 us; speedup 1.0000x reference)
//
#include <hip/hip_runtime.h>
#include <hip/hip_bf16.h>

typedef unsigned short u16;
typedef unsigned int u32;
using f32x4 = __attribute__((ext_vector_type(4))) float;
using s16x8 = __attribute__((ext_vector_type(8))) short;

#define BATCH 4
#define SEQ   4096
#define CDIM  1024
#define HDIM  64
#define QT_N  256          // 16-row q-tiles per batch

__device__ inline u16 f32_to_bf16(float f) {
    u32 u = __builtin_bit_cast(u32, f);
    u += 0x7FFFu + ((u >> 16) & 1u);
    return (u16)(u >> 16);
}
__device__ inline u32 pkbf16(float a, float b) {   // packed RNE bf16x2
    return (u32)f32_to_bf16(a) | ((u32)f32_to_bf16(b) << 16);
}
__device__ inline f32x4 mfma16(s16x8 a, s16x8 b, f32x4 c) {
    return __builtin_amdgcn_mfma_f32_16x16x32_bf16(a, b, c, 0, 0, 0);
}

// ---- Fragment-interleaved global layouts (lane = quad*16 + l16) ----
// Wtf[nt][kc][lane][8]  = Wcat[n=nt*16+l16][k=kc*32+quad*8+j]   (B-frag, n-major)
// kf [b][kt][hc][lane][8] = K[b][kt*16+l16][hc*32+quad*8+j]     (A-frag for S^T)
// qf [b][qt][hc][lane][8] = Q[b][qt*16+l16][hc*32+quad*8+j]     (B-frag for S^T)
// vf [b][kc][ht][lane][8] = V[b][kc*32+quad*8+j][ht*16+l16]     (A-frag for O^T)

// Kernel 0: W (fp32 [1024][64] x3) -> Wtf bf16 frags. 384 blocks x 64 thr.
// Wq folded scale = C^-0.5 * log2(e) (so flash uses raw v_exp_f32 = exp2).
__global__ __launch_bounds__(64) void wtrans_kernel(
        const float* __restrict__ Wk, const float* __restrict__ Wq,
        const float* __restrict__ Wv, u16* __restrict__ Wtf) {
    int bx = blockIdx.x;              // (nt, kc)
    int nt = bx >> 5, kc = bx & 31;
    int lane = threadIdx.x;
    int l16 = lane & 15, qd = lane >> 4;
    int n = nt * 16 + l16;
    int a = n >> 6, h = n & 63;
    const float* src = (a == 0) ? Wk : (a == 1) ? Wq : Wv;
    float scale = (a == 1) ? 0.045084220027780106f : 1.0f;  // 1/32 * log2(e)
    u32 p[4];
#pragma unroll
    for (int pp = 0; pp < 4; ++pp) {
        int k = kc * 32 + qd * 8 + pp * 2;
        p[pp] = pkbf16(src[k * HDIM + h] * scale, src[(k + 1) * HDIM + h] * scale);
    }
    uint4 u; u.x = p[0]; u.y = p[1]; u.z = p[2]; u.w = p[3];
    *(uint4*)&Wtf[(size_t)((nt * 32 + kc) * 64 + lane) * 8] = u;
}

// Kernel 1: projection. 512 blocks x 256 thr (4 waves). Block = 32 x-rows.
// Whole 32x1024 x-tile staged ONCE (perfect row streaming), then a
// barrier-free 32-chunk K-loop with coalesced Wtf frag loads.
__global__ __launch_bounds__(256, 2) void proj_kernel(
        const float* __restrict__ x, const u16* __restrict__ Wtf,
        u16* __restrict__ qf, u16* __restrict__ kf, u16* __restrict__ vf) {
    __shared__ __align__(16) u16 xs[32][1032];   // +8 pad: frag reads 2-way (free)
    int t = threadIdx.x, lane = t & 63, w = t >> 6;
    int quad = lane >> 4, l16 = lane & 15;
    int row0 = blockIdx.x * 32;

    const float* xb = x + (size_t)row0 * CDIM;
#pragma unroll 4
    for (int i = 0; i < 32; ++i) {       // row i: 256 thr cover 4 KB contiguous
        float4 f = *(const float4*)(xb + (size_t)i * CDIM + t * 4);
        uint2 u; u.x = pkbf16(f.x, f.y); u.y = pkbf16(f.z, f.w);
        *(uint2*)&xs[i][t * 4] = u;
    }
    __syncthreads();

    f32x4 acc[2][3];
#pragma unroll
    for (int m = 0; m < 2; ++m)
#pragma unroll
        for (int n = 0; n < 3; ++n) acc[m][n] = (f32x4){0.f, 0.f, 0.f, 0.f};

#pragma unroll 4
    for (int kc = 0; kc < 32; ++kc) {
        s16x8 a0 = *(const s16x8*)&xs[l16][kc * 32 + quad * 8];
        s16x8 a1 = *(const s16x8*)&xs[16 + l16][kc * 32 + quad * 8];
#pragma unroll
        for (int n = 0; n < 3; ++n) {
            int nt = w * 3 + n;
            s16x8 b = *(const s16x8*)&Wtf[(size_t)((nt * 32 + kc) * 64 + lane) * 8];
            acc[0][n] = mfma16(a0, b, acc[0][n]);
            acc[1][n] = mfma16(a1, b, acc[1][n]);
        }
    }
    // epilogue: scatter into fragment-interleaved kf/qf/vf
#pragma unroll
    for (int m = 0; m < 2; ++m) {
        int rbase = row0 + m * 16 + quad * 4;
        int bb = rbase >> 12, rl = rbase & 4095;
#pragma unroll
        for (int n = 0; n < 3; ++n) {
            int n0 = w * 48 + n * 16;
            if (n0 < 128) {               // k or q
                u16* dst = (n0 < 64) ? kf : qf;
                int h = (n0 & 63) + l16;
                int tt16 = rl >> 4, hc = h >> 5, qd2 = (h >> 3) & 3, j = h & 7;
                size_t base = ((size_t)((bb * 256 + tt16) * 2 + hc) * 64
                               + qd2 * 16 + (rl & 15)) * 8 + j;
#pragma unroll
                for (int r = 0; r < 4; ++r)
                    dst[base + (size_t)r * 8] = f32_to_bf16(acc[m][n][r]);
            } else {                      // v: j = rl&7 + r is contiguous -> b64
                int h0 = n0 - 128;
                int ht = h0 >> 4;
                int kc2 = rl >> 5, qdv = (rl >> 3) & 3, j0 = rl & 7;
                u32 lo = pkbf16(acc[m][n][0], acc[m][n][1]);
                u32 hi = pkbf16(acc[m][n][2], acc[m][n][3]);
                size_t base = ((size_t)((bb * 128 + kc2) * 4 + ht) * 64
                               + qdv * 16 + l16) * 8 + j0;
                uint2 u; u.x = lo; u.y = hi;
                *(uint2*)&vf[base] = u;
            }
        }
    }
}

// Kernel 2: flash attention, S^T/O^T orientation, 32 q-rows per block (two
// 16-tiles share every K/V fragment load -> half the L2 traffic of 16q).
// 512 blocks x 4 waves, wave w takes key-blocks {4i+w} of 64 keys. No LDS
// staging / no barriers in loop; P transpose via dual full-EXEC ds_bpermute
// + branchless mask select. Static-max softmax; l via ones-A MFMA.
__global__ __launch_bounds__(256, 4) void flash_kernel(
        const u16* __restrict__ qf, const u16* __restrict__ kf,
        const u16* __restrict__ vf, float* __restrict__ out) {
    __shared__ float cb[4][32][68];
    __shared__ float lb[4][32];
    int t = threadIdx.x, w = t >> 6, lane = t & 63;
    int quad = lane >> 4, l16 = lane & 15;
    int qt2 = (int)gridDim.x - 1 - (int)blockIdx.x;  // 32-row tile, heavy first
    int b = blockIdx.y;

    const u16* qp0 = qf + ((size_t)((b * QT_N + qt2 * 2) * 2) * 64 + lane) * 8;
    const u16* qp1 = qp0 + 2 * 64 * 8;     // next 16-tile
    s16x8 bq[2][2];
    bq[0][0] = *(const s16x8*)qp0;
    bq[0][1] = *(const s16x8*)(qp0 + 512);
    bq[1][0] = *(const s16x8*)qp1;
    bq[1][1] = *(const s16x8*)(qp1 + 512);
    s16x8 ones;
#pragma unroll
    for (int j = 0; j < 8; ++j) ones[j] = (short)0x3F80;

    f32x4 o[2][4], o5[2];
#pragma unroll
    for (int tl = 0; tl < 2; ++tl) {
        o5[tl] = (f32x4){0.f, 0.f, 0.f, 0.f};
#pragma unroll
        for (int i = 0; i < 4; ++i) o[tl][i] = (f32x4){0.f, 0.f, 0.f, 0.f};
    }

    int nb = (qt2 * 32 + 32 + 63) >> 6;  // 64-key causal blocks
    int iters = (nb + 3) >> 2;
    int rowq0 = qt2 * 32 + l16;          // tile0 lane q ; tile1 = +16
    const u16* kfb = kf + (size_t)b * 256 * 2 * 512;
    const u16* vfb = vf + (size_t)b * 128 * 4 * 512;
    int a0 = ((quad & 1) * 32 + l16) * 4;  // bpermute byte addrs
    int a1 = a0 + 64;
    u32 msk = (quad < 2) ? 0xFFFFFFFFu : 0u;  // tile-select mask (no branch)

    auto iteration = [&](int kb, bool domask) {
        // S^T = K Q^T : K A-frags loaded once, feed BOTH q-tiles
        f32x4 sT[2][4];
#pragma unroll
        for (int kt = 0; kt < 4; ++kt) {
            const u16* kp = kfb + ((size_t)((kb * 4 + kt) * 2) * 64 + lane) * 8;
            s16x8 k0 = *(const s16x8*)kp;
            s16x8 k1 = *(const s16x8*)(kp + 512);
            f32x4 z = (f32x4){0.f, 0.f, 0.f, 0.f};
            sT[0][kt] = mfma16(k1, bq[0][1], mfma16(k0, bq[0][0], z));
            sT[1][kt] = mfma16(k1, bq[1][1], mfma16(k0, bq[1][0], z));
        }
        // exp2 (scale+log2e folded into Wq), mask only diagonal block, pack
        u32 P01[2][4], P23[2][4];
#pragma unroll
        for (int tl = 0; tl < 2; ++tl) {
            int rowq = rowq0 + tl * 16;
#pragma unroll
            for (int kt = 0; kt < 4; ++kt) {
                float e[4];
#pragma unroll
                for (int r = 0; r < 4; ++r) {
                    float ev = __builtin_amdgcn_exp2f(sT[tl][kt][r]);
                    if (domask) {
                        int key = kb * 64 + kt * 16 + quad * 4 + r;
                        ev = (key > rowq) ? 0.f : ev;
                    }
                    e[r] = ev;
                }
                P01[tl][kt] = pkbf16(e[0], e[1]);
                P23[tl][kt] = pkbf16(e[2], e[3]);
            }
        }
        // per 32-key chunk: V A-frags shared by both tiles; P^T via dual
        // full-EXEC bpermute + branchless select; O^T += V^T P^T; l += 1P^T
#pragma unroll
        for (int c = 0; c < 2; ++c) {
            s16x8 vA[4];
#pragma unroll
            for (int ht = 0; ht < 4; ++ht)
                vA[ht] = *(const s16x8*)&vfb[((size_t)((kb * 2 + c) * 4 + ht) * 64
                                             + lane) * 8];
            int t0 = 2 * c, t1 = 2 * c + 1;
#pragma unroll
            for (int tl = 0; tl < 2; ++tl) {
                u32 x0 = (u32)__builtin_amdgcn_ds_bpermute(a0, (int)P01[tl][t0]);
                u32 y0 = (u32)__builtin_amdgcn_ds_bpermute(a0, (int)P01[tl][t1]);
                u32 x1 = (u32)__builtin_amdgcn_ds_bpermute(a0, (int)P23[tl][t0]);
                u32 y1 = (u32)__builtin_amdgcn_ds_bpermute(a0, (int)P23[tl][t1]);
                u32 x2 = (u32)__builtin_amdgcn_ds_bpermute(a1, (int)P01[tl][t0]);
                u32 y2 = (u32)__builtin_amdgcn_ds_bpermute(a1, (int)P01[tl][t1]);
                u32 x3 = (u32)__builtin_amdgcn_ds_bpermute(a1, (int)P23[tl][t0]);
                u32 y3 = (u32)__builtin_amdgcn_ds_bpermute(a1, (int)P23[tl][t1]);
                uint4 pu;
                pu.x = (x0 & msk) | (y0 & ~msk);
                pu.y = (x1 & msk) | (y1 & ~msk);
                pu.z = (x2 & msk) | (y2 & ~msk);
                pu.w = (x3 & msk) | (y3 & ~msk);
                s16x8 pb = __builtin_bit_cast(s16x8, pu);
#pragma unroll
                for (int ht = 0; ht < 4; ++ht)
                    o[tl][ht] = mfma16(vA[ht], pb, o[tl][ht]);
                o5[tl] = mfma16(ones, pb, o5[tl]);
            }
        }
    };

    for (int i = 0; i < iters - 1; ++i) iteration(4 * i + w, false);
    {
        int kb = 4 * (iters - 1) + w;
        if (kb < nb) iteration(kb, true);   // mask harmless for full blocks
    }
    // combine 4 key-split partials (static max: pure addition)
#pragma unroll
    for (int tl = 0; tl < 2; ++tl) {
#pragma unroll
        for (int ht = 0; ht < 4; ++ht)
#pragma unroll
            for (int r = 0; r < 4; ++r)
                cb[w][tl * 16 + l16][ht * 16 + quad * 4 + r] = o[tl][ht][r];
        if (quad == 0) lb[w][tl * 16 + l16] = o5[tl][0];
    }
    __syncthreads();
    int row = t >> 3, c0 = (t & 7) * 8;    // 256 thr cover 32 rows x 64 cols
    float l = lb[0][row] + lb[1][row] + lb[2][row] + lb[3][row];
    float rcp = 1.0f / l;
    float4 s0 = (float4){0.f, 0.f, 0.f, 0.f}, s1 = s0;
#pragma unroll
    for (int w4 = 0; w4 < 4; ++w4) {
        float4 p0 = *(const float4*)&cb[w4][row][c0];
        float4 p1 = *(const float4*)&cb[w4][row][c0 + 4];
        s0.x += p0.x; s0.y += p0.y; s0.z += p0.z; s0.w += p0.w;
        s1.x += p1.x; s1.y += p1.y; s1.z += p1.z; s1.w += p1.w;
    }
    s0.x *= rcp; s0.y *= rcp; s0.z *= rcp; s0.w *= rcp;
    s1.x *= rcp; s1.y *= rcp; s1.z *= rcp; s1.w *= rcp;
    float* op = &out[((size_t)(b * SEQ) + qt2 * 32 + row) * HDIM + c0];
    *(float4*)op = s0;
    *(float4*)(op + 4) = s1;
}

extern "C" void kernel_launch(void* const* d_in, const int* in_sizes, int n_in,
                              void* d_out, int out_size, void* d_ws, size_t ws_size,
                              hipStream_t stream) {
    const float* x  = (const float*)d_in[0];
    const float* Wk = (const float*)d_in[1];
    const float* Wq = (const float*)d_in[2];
    const float* Wv = (const float*)d_in[3];
    u16* wsu = (u16*)d_ws;
    u16* Wtf = wsu;                         // 12*32*64*8      = 196608 u16
    u16* kf  = Wtf + 196608;                // 4*256*2*64*8    = 1048576
    u16* qf  = kf + 1048576;
    u16* vf  = qf + 1048576;                // 4*128*4*64*8    = 1048576
    float* out = (float*)d_out;

    hipLaunchKernelGGL(wtrans_kernel, dim3(384), dim3(64), 0, stream, Wk, Wq, Wv, Wtf);
    hipLaunchKernelGGL(proj_kernel, dim3(512), dim3(256), 0, stream, x, Wtf, qf, kf, vf);
    hipLaunchKernelGGL(flash_kernel, dim3(SEQ / 32, BATCH), dim3(256), 0, stream, qf, kf, vf, out);
}

// Round 11
// 133.464 us; speedup vs baseline: 1.1028x; 1.1028x over previous
//
#include <hip/hip_runtime.h>
#include <hip/hip_bf16.h>

typedef unsigned short u16;
typedef unsigned int u32;
using f32x4 = __attribute__((ext_vector_type(4))) float;
using s16x8 = __attribute__((ext_vector_type(8))) short;

#define BATCH 4
#define SEQ   4096
#define CDIM  1024
#define HDIM  64
#define QT_N  256          // 16-row q-tiles per batch

__device__ inline u16 f32_to_bf16(float f) {
    u32 u = __builtin_bit_cast(u32, f);
    u += 0x7FFFu + ((u >> 16) & 1u);
    return (u16)(u >> 16);
}
__device__ inline u32 pkbf16(float a, float b) {   // packed RNE bf16x2
    return (u32)f32_to_bf16(a) | ((u32)f32_to_bf16(b) << 16);
}
__device__ inline f32x4 mfma16(s16x8 a, s16x8 b, f32x4 c) {
    return __builtin_amdgcn_mfma_f32_16x16x32_bf16(a, b, c, 0, 0, 0);
}

// ---- Fragment-interleaved global layouts (lane = quad*16 + l16) ----
// Wtf[nt][kc][lane][8]  = Wcat[n=nt*16+l16][k=kc*32+quad*8+j]   (B-frag, n-major)
// kf [b][kt][hc][lane][8] = K[b][kt*16+l16][hc*32+quad*8+j]     (A-frag for S^T)
// qf [b][qt][hc][lane][8] = Q[b][qt*16+l16][hc*32+quad*8+j]     (B-frag for S^T)
// vf [b][kc][ht][lane][8] = V[b][kc*32+quad*8+j][ht*16+l16]     (A-frag for O^T)

// Kernel 0: W (fp32 [1024][64] x3) -> Wtf bf16 frags. 384 blocks x 64 thr.
__global__ __launch_bounds__(64) void wtrans_kernel(
        const float* __restrict__ Wk, const float* __restrict__ Wq,
        const float* __restrict__ Wv, u16* __restrict__ Wtf) {
    int bx = blockIdx.x;              // (nt, kc)
    int nt = bx >> 5, kc = bx & 31;
    int lane = threadIdx.x;
    int l16 = lane & 15, qd = lane >> 4;
    int n = nt * 16 + l16;
    int a = n >> 6, h = n & 63;
    const float* src = (a == 0) ? Wk : (a == 1) ? Wq : Wv;
    float scale = (a == 1) ? 0.045084220027780106f : 1.0f;  // 1/32 * log2(e)
    u32 p[4];
#pragma unroll
    for (int pp = 0; pp < 4; ++pp) {
        int k = kc * 32 + qd * 8 + pp * 2;
        p[pp] = pkbf16(src[k * HDIM + h] * scale, src[(k + 1) * HDIM + h] * scale);
    }
    uint4 u; u.x = p[0]; u.y = p[1]; u.z = p[2]; u.w = p[3];
    *(uint4*)&Wtf[(size_t)((nt * 32 + kc) * 64 + lane) * 8] = u;
}

// Kernel 1: projection. 1024 blocks x 256 thr (4 waves), 16 x-rows per block
// (33 KB LDS -> 4 blocks/CU = 16 waves/CU; round-10 32-row version was
// 2 blocks/CU and latency-starved). Stage once, barrier-free 32-chunk K-loop.
__global__ __launch_bounds__(256, 4) void proj_kernel(
        const float* __restrict__ x, const u16* __restrict__ Wtf,
        u16* __restrict__ qf, u16* __restrict__ kf, u16* __restrict__ vf) {
    __shared__ __align__(16) u16 xs[16][1032];   // +8 pad: frag reads 2-way (free)
    int t = threadIdx.x, lane = t & 63, w = t >> 6;
    int quad = lane >> 4, l16 = lane & 15;
    int row0 = blockIdx.x * 16;

    const float* xb = x + (size_t)row0 * CDIM;
#pragma unroll 4
    for (int i = 0; i < 16; ++i) {       // row i: 256 thr cover 4 KB contiguous
        float4 f = *(const float4*)(xb + (size_t)i * CDIM + t * 4);
        uint2 u; u.x = pkbf16(f.x, f.y); u.y = pkbf16(f.z, f.w);
        *(uint2*)&xs[i][t * 4] = u;
    }
    __syncthreads();

    f32x4 acc[3];
#pragma unroll
    for (int n = 0; n < 3; ++n) acc[n] = (f32x4){0.f, 0.f, 0.f, 0.f};

#pragma unroll 4
    for (int kc = 0; kc < 32; ++kc) {
        s16x8 a0 = *(const s16x8*)&xs[l16][kc * 32 + quad * 8];
#pragma unroll
        for (int n = 0; n < 3; ++n) {
            int nt = w * 3 + n;
            s16x8 b = *(const s16x8*)&Wtf[(size_t)((nt * 32 + kc) * 64 + lane) * 8];
            acc[n] = mfma16(a0, b, acc[n]);
        }
    }
    // epilogue: scatter into fragment-interleaved kf/qf/vf
    int rbase = row0 + quad * 4;          // C-layout: row = quad*4+r, col = l16
    int bb = rbase >> 12, rl = rbase & 4095;
#pragma unroll
    for (int n = 0; n < 3; ++n) {
        int n0 = w * 48 + n * 16;
        if (n0 < 128) {                   // k or q
            u16* dst = (n0 < 64) ? kf : qf;
            int h = (n0 & 63) + l16;
            int tt16 = rl >> 4, hc = h >> 5, qd2 = (h >> 3) & 3, j = h & 7;
            size_t base = ((size_t)((bb * 256 + tt16) * 2 + hc) * 64
                           + qd2 * 16 + (rl & 15)) * 8 + j;
#pragma unroll
            for (int r = 0; r < 4; ++r)
                dst[base + (size_t)r * 8] = f32_to_bf16(acc[n][r]);
        } else {                          // v: j = rl&7 + r contiguous -> b64
            int h0 = n0 - 128;
            int ht = h0 >> 4;
            int kc2 = rl >> 5, qdv = (rl >> 3) & 3, j0 = rl & 7;
            u32 lo = pkbf16(acc[n][0], acc[n][1]);
            u32 hi = pkbf16(acc[n][2], acc[n][3]);
            size_t base = ((size_t)((bb * 128 + kc2) * 4 + ht) * 64
                           + qdv * 16 + l16) * 8 + j0;
            uint2 u; u.x = lo; u.y = hi;
            *(uint2*)&vf[base] = u;
        }
    }
}

// Kernel 2: flash attention, S^T/O^T orientation, 32 q-rows per block,
// 8-WAY key split (512 thr): 4096 waves -> 4 waves/SIMD to hide the
// load->MFMA->exp->bpermute->MFMA chain (round-10 had only 2/SIMD). No LDS
// staging / no barriers in loop; P transpose via dual full-EXEC ds_bpermute
// + branchless mask select. Static-max softmax; l via ones-A MFMA.
__global__ __launch_bounds__(512, 4) void flash_kernel(
        const u16* __restrict__ qf, const u16* __restrict__ kf,
        const u16* __restrict__ vf, float* __restrict__ out) {
    __shared__ float cb[8][32][68];
    __shared__ float lb[8][32];
    int t = threadIdx.x, w = t >> 6, lane = t & 63;
    int quad = lane >> 4, l16 = lane & 15;
    int qt2 = (int)gridDim.x - 1 - (int)blockIdx.x;  // 32-row tile, heavy first
    int b = blockIdx.y;

    const u16* qp0 = qf + ((size_t)((b * QT_N + qt2 * 2) * 2) * 64 + lane) * 8;
    const u16* qp1 = qp0 + 2 * 64 * 8;     // next 16-tile
    s16x8 bq[2][2];
    bq[0][0] = *(const s16x8*)qp0;
    bq[0][1] = *(const s16x8*)(qp0 + 512);
    bq[1][0] = *(const s16x8*)qp1;
    bq[1][1] = *(const s16x8*)(qp1 + 512);
    s16x8 ones;
#pragma unroll
    for (int j = 0; j < 8; ++j) ones[j] = (short)0x3F80;

    f32x4 o[2][4], o5[2];
#pragma unroll
    for (int tl = 0; tl < 2; ++tl) {
        o5[tl] = (f32x4){0.f, 0.f, 0.f, 0.f};
#pragma unroll
        for (int i = 0; i < 4; ++i) o[tl][i] = (f32x4){0.f, 0.f, 0.f, 0.f};
    }

    int nb = (qt2 * 32 + 32 + 63) >> 6;  // 64-key causal blocks
    int iters = (nb + 7) >> 3;
    int rowq0 = qt2 * 32 + l16;          // tile0 lane q ; tile1 = +16
    const u16* kfb = kf + (size_t)b * 256 * 2 * 512;
    const u16* vfb = vf + (size_t)b * 128 * 4 * 512;
    int a0 = ((quad & 1) * 32 + l16) * 4;  // bpermute byte addrs
    int a1 = a0 + 64;
    u32 msk = (quad < 2) ? 0xFFFFFFFFu : 0u;  // tile-select mask (no branch)

    auto iteration = [&](int kb, bool domask) {
        // S^T = K Q^T : K A-frags loaded once, feed BOTH q-tiles
        f32x4 sT[2][4];
#pragma unroll
        for (int kt = 0; kt < 4; ++kt) {
            const u16* kp = kfb + ((size_t)((kb * 4 + kt) * 2) * 64 + lane) * 8;
            s16x8 k0 = *(const s16x8*)kp;
            s16x8 k1 = *(const s16x8*)(kp + 512);
            f32x4 z = (f32x4){0.f, 0.f, 0.f, 0.f};
            sT[0][kt] = mfma16(k1, bq[0][1], mfma16(k0, bq[0][0], z));
            sT[1][kt] = mfma16(k1, bq[1][1], mfma16(k0, bq[1][0], z));
        }
        // exp2 (scale+log2e folded into Wq), mask only diagonal block, pack
        u32 P01[2][4], P23[2][4];
#pragma unroll
        for (int tl = 0; tl < 2; ++tl) {
            int rowq = rowq0 + tl * 16;
#pragma unroll
            for (int kt = 0; kt < 4; ++kt) {
                float e[4];
#pragma unroll
                for (int r = 0; r < 4; ++r) {
                    float ev = __builtin_amdgcn_exp2f(sT[tl][kt][r]);
                    if (domask) {
                        int key = kb * 64 + kt * 16 + quad * 4 + r;
                        ev = (key > rowq) ? 0.f : ev;
                    }
                    e[r] = ev;
                }
                P01[tl][kt] = pkbf16(e[0], e[1]);
                P23[tl][kt] = pkbf16(e[2], e[3]);
            }
        }
        // per 32-key chunk: V A-frags shared by both tiles; P^T via dual
        // full-EXEC bpermute + branchless select; O^T += V^T P^T; l += 1P^T
#pragma unroll
        for (int c = 0; c < 2; ++c) {
            s16x8 vA[4];
#pragma unroll
            for (int ht = 0; ht < 4; ++ht)
                vA[ht] = *(const s16x8*)&vfb[((size_t)((kb * 2 + c) * 4 + ht) * 64
                                             + lane) * 8];
            int t0 = 2 * c, t1 = 2 * c + 1;
#pragma unroll
            for (int tl = 0; tl < 2; ++tl) {
                u32 x0 = (u32)__builtin_amdgcn_ds_bpermute(a0, (int)P01[tl][t0]);
                u32 y0 = (u32)__builtin_amdgcn_ds_bpermute(a0, (int)P01[tl][t1]);
                u32 x1 = (u32)__builtin_amdgcn_ds_bpermute(a0, (int)P23[tl][t0]);
                u32 y1 = (u32)__builtin_amdgcn_ds_bpermute(a0, (int)P23[tl][t1]);
                u32 x2 = (u32)__builtin_amdgcn_ds_bpermute(a1, (int)P01[tl][t0]);
                u32 y2 = (u32)__builtin_amdgcn_ds_bpermute(a1, (int)P01[tl][t1]);
                u32 x3 = (u32)__builtin_amdgcn_ds_bpermute(a1, (int)P23[tl][t0]);
                u32 y3 = (u32)__builtin_amdgcn_ds_bpermute(a1, (int)P23[tl][t1]);
                uint4 pu;
                pu.x = (x0 & msk) | (y0 & ~msk);
                pu.y = (x1 & msk) | (y1 & ~msk);
                pu.z = (x2 & msk) | (y2 & ~msk);
                pu.w = (x3 & msk) | (y3 & ~msk);
                s16x8 pb = __builtin_bit_cast(s16x8, pu);
#pragma unroll
                for (int ht = 0; ht < 4; ++ht)
                    o[tl][ht] = mfma16(vA[ht], pb, o[tl][ht]);
                o5[tl] = mfma16(ones, pb, o5[tl]);
            }
        }
    };

    for (int i = 0; i < iters - 1; ++i) iteration(8 * i + w, false);
    {
        int kb = 8 * (iters - 1) + w;
        if (kb < nb) iteration(kb, true);   // mask harmless for full blocks
    }
    // combine 8 key-split partials (static max: pure addition)
#pragma unroll
    for (int tl = 0; tl < 2; ++tl) {
#pragma unroll
        for (int ht = 0; ht < 4; ++ht)
#pragma unroll
            for (int r = 0; r < 4; ++r)
                cb[w][tl * 16 + l16][ht * 16 + quad * 4 + r] = o[tl][ht][r];
        if (quad == 0) lb[w][tl * 16 + l16] = o5[tl][0];
    }
    __syncthreads();
    int row = t >> 4, c0 = (t & 15) * 4;   // 512 thr cover 32 rows x 64 cols
    float l = 0.f;
    float4 s = (float4){0.f, 0.f, 0.f, 0.f};
#pragma unroll
    for (int w8 = 0; w8 < 8; ++w8) {
        l += lb[w8][row];
        float4 p = *(const float4*)&cb[w8][row][c0];
        s.x += p.x; s.y += p.y; s.z += p.z; s.w += p.w;
    }
    float rcp = 1.0f / l;
    s.x *= rcp; s.y *= rcp; s.z *= rcp; s.w *= rcp;
    *(float4*)&out[((size_t)(b * SEQ) + qt2 * 32 + row) * HDIM + c0] = s;
}

extern "C" void kernel_launch(void* const* d_in, const int* in_sizes, int n_in,
                              void* d_out, int out_size, void* d_ws, size_t ws_size,
                              hipStream_t stream) {
    const float* x  = (const float*)d_in[0];
    const float* Wk = (const float*)d_in[1];
    const float* Wq = (const float*)d_in[2];
    const float* Wv = (const float*)d_in[3];
    u16* wsu = (u16*)d_ws;
    u16* Wtf = wsu;                         // 12*32*64*8      = 196608 u16
    u16* kf  = Wtf + 196608;                // 4*256*2*64*8    = 1048576
    u16* qf  = kf + 1048576;
    u16* vf  = qf + 1048576;                // 4*128*4*64*8    = 1048576
    float* out = (float*)d_out;

    hipLaunchKernelGGL(wtrans_kernel, dim3(384), dim3(64), 0, stream, Wk, Wq, Wv, Wtf);
    hipLaunchKernelGGL(proj_kernel, dim3(1024), dim3(256), 0, stream, x, Wtf, qf, kf, vf);
    hipLaunchKernelGGL(flash_kernel, dim3(SEQ / 32, BATCH), dim3(512), 0, stream, qf, kf, vf, out);
}